// Round 9
// baseline (871.349 us; speedup 1.0000x reference)
//
#include <hip/hip_runtime.h>
#include <stdint.h>
#include <math.h>

#define D_MODEL 1024
#define D_STATE 128
#define D_INNER 2048
#define DT_RANK 64
#define BATCH   2
#define SEQ     2048
#define TOKENS  (BATCH*SEQ)        // 4096
#define NPROJ   (DT_RANK + 2*D_STATE) // 320
#define NCOL    (BATCH*D_INNER)    // 4096 scan columns

typedef unsigned short u16;
typedef __attribute__((ext_vector_type(4))) float f32x4;
typedef __attribute__((ext_vector_type(8))) short s16x8;
typedef __attribute__((ext_vector_type(4))) unsigned short u16x4;

#if __has_builtin(__builtin_amdgcn_exp2f)
#define EXP2(x) __builtin_amdgcn_exp2f(x)
#else
#define EXP2(x) __expf((x) * 0.6931471805599453f)
#endif
#define L2E 1.44269504088896f

static __device__ __forceinline__ u16 f2bf(float f) {
  unsigned u = __builtin_bit_cast(unsigned, f);
  return (u16)((u + 0x7FFFu + ((u >> 16) & 1u)) >> 16);
}
static __device__ __forceinline__ float bf2f(u16 h) {
  return __builtin_bit_cast(float, ((unsigned)h) << 16);
}

static __device__ __forceinline__ void gload_lds16(const void* g, void* l) {
  __builtin_amdgcn_global_load_lds(
      (const __attribute__((address_space(1))) void*)g,
      (__attribute__((address_space(3))) void*)l, 16, 0, 0);
}

// DPP add: x + dpp_shuffle(x)
template<int CTRL>
static __device__ __forceinline__ float dpp_add(float x) {
  int t = __builtin_amdgcn_update_dpp(0, __builtin_bit_cast(int, x), CTRL, 0xf, 0xf, true);
  return x + __builtin_bit_cast(float, t);
}
// sum over each 8-lane octet; valid in lane 8o+4 of each octet
static __device__ __forceinline__ float octet_sum(float x) {
  x = dpp_add<0xB1>(x);   // quad_perm(1,0,3,2): pair sum
  x = dpp_add<0x4E>(x);   // quad_perm(2,3,0,1): quad sum
  x = dpp_add<0x114>(x);  // row_shr:4: lanes q1,q3 hold quad(i)+quad(i-1)
  return x;
}

// ---------------- fp32 -> bf16 convert (vec4) ----------------
__global__ void k_cvt_bf16(const float* __restrict__ in, u16* __restrict__ out, int n4) {
  int i = blockIdx.x * blockDim.x + threadIdx.x;
  if (i >= n4) return;
  f32x4 v = ((const f32x4*)in)[i];
  u16x4 o;
  o.x = f2bf(v.x); o.y = f2bf(v.y); o.z = f2bf(v.z); o.w = f2bf(v.w);
  ((u16x4*)out)[i] = o;
}

// ---------------- bf16 GEMM: C = A @ B^T ----------------
// EPI: 0 = f32 store, 1 = bf16 store,
//      3 = dt path: v=softplus(acc+2*bias[col]);
//          dtq[(col/4)][row][col%4] = {v*l2e, v*u};  R same layout = e^{-v}
#define BM 128
#define BN 128
#define BK 64

template<int EPI>
__global__ __launch_bounds__(256) void k_gemm_bt(
    const u16* __restrict__ A, const u16* __restrict__ B,
    void* __restrict__ C, const float* __restrict__ bias,
    const u16* __restrict__ U, float* __restrict__ Rout,
    int M, int N, int K, int ldc)
{
  __shared__ __align__(16) u16 As[BM*BK];
  __shared__ __align__(16) u16 Bs[BN*BK];
  const int tid  = threadIdx.x;
  const int lane = tid & 63;
  const int wid  = tid >> 6;
  const int wr   = (wid >> 1) * 64;
  const int wc   = (wid & 1) * 64;
  const int bm   = blockIdx.x * BM;
  const int bn   = blockIdx.y * BN;
  const int lr   = lane & 15;
  const int lk   = (lane >> 4) * 8;

  f32x4 acc[4][4] = {};

  for (int k0 = 0; k0 < K; k0 += BK) {
    #pragma unroll
    for (int i = 0; i < 4; ++i) {
      int c   = tid + i * 256;
      int row = c >> 3;
      int col = (c & 7) * 8;
      const u16* ga = A + (size_t)(bm + row) * K + (k0 + col);
      gload_lds16(ga, As + (size_t)c * 8);
      int brow = bn + row; brow = brow < N ? brow : N - 1;
      const u16* gb = B + (size_t)brow * K + (k0 + col);
      gload_lds16(gb, Bs + (size_t)c * 8);
    }
    __syncthreads();

    #pragma unroll
    for (int kk = 0; kk < BK; kk += 32) {
      s16x8 af[4], bf[4];
      #pragma unroll
      for (int m = 0; m < 4; ++m)
        af[m] = *(const s16x8*)(As + (size_t)(wr + m*16 + lr) * BK + kk + lk);
      #pragma unroll
      for (int n = 0; n < 4; ++n)
        bf[n] = *(const s16x8*)(Bs + (size_t)(wc + n*16 + lr) * BK + kk + lk);
      #pragma unroll
      for (int m = 0; m < 4; ++m)
        #pragma unroll
        for (int n = 0; n < 4; ++n)
          acc[m][n] = __builtin_amdgcn_mfma_f32_16x16x32_bf16(af[m], bf[n], acc[m][n], 0, 0, 0);
    }
    __syncthreads();
  }

  const int orow0 = bm + wr + (lane >> 4) * 4;
  const int ocol0 = bn + wc + lr;
  #pragma unroll
  for (int m = 0; m < 4; ++m) {
    #pragma unroll
    for (int n = 0; n < 4; ++n) {
      int col = ocol0 + n * 16;
      if (col >= N) continue;
      #pragma unroll
      for (int r = 0; r < 4; ++r) {
        int row = orow0 + m * 16 + r;
        float v = acc[m][n][r];
        if (EPI == 3) {
          v = v + 2.0f * bias[col];
          v = (v > 20.0f) ? v : log1pf(__expf(v));
          float uu = bf2f(U[(size_t)row * D_INNER + col]);
          size_t pi = (((size_t)(col >> 2) * TOKENS + row) << 2) + (col & 3);
          ((float2*)C)[pi] = make_float2(v * L2E, v * uu);
          Rout[pi] = EXP2(-v * L2E);
        } else if (EPI == 1) {
          ((u16*)C)[(size_t)row * ldc + col] = f2bf(v);
        } else {
          ((float*)C)[(size_t)row * ldc + col] = v;
        }
      }
    }
  }
}

// ---------------- depthwise causal conv (K=4) + SiLU ----------------
__global__ __launch_bounds__(256) void k_conv_silu(
    const u16* __restrict__ xz, const float* __restrict__ cw,
    const float* __restrict__ cb, u16* __restrict__ u)
{
  int idx = blockIdx.x * 256 + threadIdx.x;
  int d   = idx & (D_INNER - 1);
  int tok = idx >> 11;
  int t   = tok & (SEQ - 1);
  int b   = tok >> 11;
  f32x4 w = *(const f32x4*)(cw + (size_t)d * 4);
  float acc = cb[d];
  #pragma unroll
  for (int j = 0; j < 4; ++j) {
    int tt = t - 3 + j;
    if (tt >= 0)
      acc += bf2f(xz[(size_t)(b * SEQ + tt) * (2*D_INNER) + d]) * w[j];
  }
  float s = acc / (1.0f + __expf(-acc));
  u[(size_t)tok * D_INNER + d] = f2bf(s);
}

// ---------------- split x_dbl -> dtlo bf16, interleaved BC f32 ----------------
// BC per token (256 f32): lane l gets {B2l, B2l+1, C2l, C2l+1} at 4*l
__global__ void k_split(const float* __restrict__ xdbl, u16* __restrict__ dtlo,
                        float* __restrict__ BC)
{
  int idx = blockIdx.x * 256 + threadIdx.x;
  if (idx >= TOKENS * NPROJ) return;
  int row = idx / NPROJ;
  int c   = idx - row * NPROJ;
  float v = xdbl[idx];
  if (c < DT_RANK) {
    dtlo[(size_t)row * DT_RANK + c] = f2bf(v);
  } else if (c < DT_RANK + D_STATE) {
    int n = c - DT_RANK;
    BC[(size_t)row * 256 + (n >> 1) * 4 + (n & 1)] = v;
  } else {
    int n = c - DT_RANK - D_STATE;
    BC[(size_t)row * 256 + (n >> 1) * 4 + 2 + (n & 1)] = v;
  }
}

// =================== segmented selective scan (NC=4 cols/wave) ===================
// dtqP: float2 {dt*l2e, dt*u} packed [d/4][tok][d%4]; R: e^{-dt} same layout (f32)
// BC:   f32 interleaved [b][t][256]  ({B2l,B2l+1,C2l,C2l+1} per lane)
// H:    [col][nseg][128]; S: [col][nseg] (sum of dt*l2e)
// Lane holds states {2*lane, 2*lane+1} for each of 4 cols; dA1 = dA0 * e^{-dt}.
#define NC 4
#define HCHUNK 8
#define RSTR 36   // 8 octets * 4 cols + 4 pad: 2-way banks on read (free)

__global__ __launch_bounds__(256, 8) void k_scan_head(
    const float* __restrict__ dtqP, const float* __restrict__ R,
    const float* __restrict__ BC, const float* __restrict__ A_log,
    float* __restrict__ H, float* __restrict__ S, int nseg, int SL)
{
  const int lane = threadIdx.x & 63;
  const int wid  = threadIdx.x >> 6;
  const int bid  = blockIdx.x;
  const int nsm1 = nseg - 1;
  const int grp  = bid / nsm1;
  const int s    = bid - grp * nsm1;
  const int col0 = grp * 16 + wid * NC;
  const int b    = col0 >> 11;
  const int d0   = col0 & (D_INNER - 1);

  float A0[NC];
  #pragma unroll
  for (int c = 0; c < NC; ++c)
    A0[c] = -__expf(A_log[(size_t)(d0 + c) * D_STATE + 2 * lane]);
  float h0[NC] = {}, h1[NC] = {}, sum[NC] = {};

  const float* dq = dtqP + ((size_t)(d0 >> 2) * TOKENS + (size_t)b * SEQ + s * SL) * 8;
  const float* rp = R    + ((size_t)(d0 >> 2) * TOKENS + (size_t)b * SEQ + s * SL) * 4;
  asm("" : "+v"(dq));
  asm("" : "+v"(rp));
  const float* BCb = BC + ((size_t)b * SEQ + s * SL) * 256 + 4 * lane;

  for (int c0 = 0; c0 < SL; c0 += 4) {
    #pragma unroll
    for (int tt = 0; tt < 4; ++tt) {
      const float* dqq = dq + (size_t)(c0 + tt) * 8;
      f32x4 q0 = *(const f32x4*)(dqq);
      f32x4 q1 = *(const f32x4*)(dqq + 4);
      f32x4 rr = *(const f32x4*)(rp + (size_t)(c0 + tt) * 4);
      float2 bb = *(const float2*)(BCb + (size_t)(c0 + tt) * 256);
      float dts[NC] = {q0.x, q0.z, q1.x, q1.z};
      float dus[NC] = {q0.y, q0.w, q1.y, q1.w};
      #pragma unroll
      for (int c = 0; c < NC; ++c) {
        sum[c] += dts[c];
        float dA0 = EXP2(dts[c] * A0[c]);
        float dA1 = dA0 * rr[c];
        h0[c] = fmaf(dA0, h0[c], dus[c] * bb.x);
        h1[c] = fmaf(dA1, h1[c], dus[c] * bb.y);
      }
    }
  }
  #pragma unroll
  for (int c = 0; c < NC; ++c)
    *(float2*)(H + ((size_t)(col0 + c) * nseg + s) * D_STATE + 2 * lane) =
        make_float2(h0[c], h1[c]);
  if (lane == 0) {
    #pragma unroll
    for (int c = 0; c < NC; ++c)
      S[(size_t)(col0 + c) * nseg + s] = sum[c];
  }
}

__global__ __launch_bounds__(256) void k_stitch(
    const float* __restrict__ A_log, float* __restrict__ H,
    const float* __restrict__ S, int nseg)
{
  const int lane = threadIdx.x & 63;
  const int wid  = threadIdx.x >> 6;
  const int col  = blockIdx.x * 4 + wid;
  const int d = col & (D_INNER - 1);

  float2 al = *(const float2*)(A_log + (size_t)d * D_STATE + 2 * lane);
  const float A0 = -__expf(al.x);
  const float A1 = -__expf(al.y);
  float hin0 = 0.f, hin1 = 0.f;

  for (int s = 0; s < nseg - 1; ++s) {
    float2* hp = (float2*)(H + ((size_t)col * nseg + s) * D_STATE + 2 * lane);
    float2 he = *hp;
    float sm = S[(size_t)col * nseg + s];
    float d0 = EXP2(A0 * sm);
    float d1 = EXP2(A1 * sm);
    hin0 = fmaf(d0, hin0, he.x);
    hin1 = fmaf(d1, hin1, he.y);
    *hp = make_float2(hin0, hin1);
  }
}

__global__ __launch_bounds__(256, 8) void k_scan_main(
    const float* __restrict__ dtqP, const float* __restrict__ R,
    const float* __restrict__ BC, const float* __restrict__ A_log,
    const float* __restrict__ H, u16* __restrict__ ysT,
    int nseg, int lognseg, int SL)
{
  __shared__ float reds[4][HCHUNK * RSTR];   // 4 x 1152B
  __shared__ u16 ybufs[4][NC * 128];         // 4 x 1KB
  const int lane = threadIdx.x & 63;
  const int wid  = threadIdx.x >> 6;
  const unsigned bid = blockIdx.x;
  const int seg  = bid & (nseg - 1);
  const int grp  = bid >> lognseg;
  const int col0 = grp * 16 + wid * NC;
  const int b    = col0 >> 11;
  const int d0   = col0 & (D_INNER - 1);

  float A0[NC];
  #pragma unroll
  for (int c = 0; c < NC; ++c)
    A0[c] = -__expf(A_log[(size_t)(d0 + c) * D_STATE + 2 * lane]);
  float h0[NC] = {}, h1[NC] = {};
  if (seg > 0) {
    #pragma unroll
    for (int c = 0; c < NC; ++c) {
      float2 hv = *(const float2*)(H + ((size_t)(col0 + c) * nseg + seg - 1) * D_STATE + 2 * lane);
      h0[c] = hv.x; h1[c] = hv.y;
    }
  }

  const int t0g = seg * SL;
  const float* dq = dtqP + ((size_t)(d0 >> 2) * TOKENS + (size_t)b * SEQ + t0g) * 8;
  const float* rp = R    + ((size_t)(d0 >> 2) * TOKENS + (size_t)b * SEQ + t0g) * 4;
  asm("" : "+v"(dq));
  asm("" : "+v"(rp));
  const float* BCb = BC + ((size_t)b * SEQ + t0g) * 256 + 4 * lane;
  float* red = reds[wid];
  u16* ybuf = ybufs[wid];
  const int o  = lane & 31;
  const int sr = o >> 2;       // step within chunk this lane reduces
  const int cr = o & 3;        // col this lane reduces
  const int hf = lane >> 5;    // which 4 octets this lane sums
  const bool wlane = (lane & 7) == 4;   // octet writer
  const int oct = lane >> 3;
  u16* yo = ysT + ((size_t)d0 * BATCH + b) * SEQ + t0g;

  for (int c0 = 0; c0 < SL; c0 += HCHUNK) {
    #pragma unroll
    for (int tt = 0; tt < HCHUNK; ++tt) {
      const float* dqq = dq + (size_t)(c0 + tt) * 8;
      f32x4 q0 = *(const f32x4*)(dqq);
      f32x4 q1 = *(const f32x4*)(dqq + 4);
      f32x4 rr = *(const f32x4*)(rp + (size_t)(c0 + tt) * 4);
      f32x4 bc = *(const f32x4*)(BCb + (size_t)(c0 + tt) * 256);
      float dts[NC] = {q0.x, q0.z, q1.x, q1.z};
      float dus[NC] = {q0.y, q0.w, q1.y, q1.w};
      f32x4 p;
      #pragma unroll
      for (int c = 0; c < NC; ++c) {
        float dA0 = EXP2(dts[c] * A0[c]);
        float dA1 = dA0 * rr[c];
        h0[c] = fmaf(dA0, h0[c], dus[c] * bc.x);
        h1[c] = fmaf(dA1, h1[c], dus[c] * bc.y);
        p[c] = fmaf(h1[c], bc.w, h0[c] * bc.z);
      }
      // in-register octet reduction (VALU pipe), then 1/8 LDS traffic
      #pragma unroll
      for (int c = 0; c < NC; ++c) p[c] = octet_sum(p[c]);
      if (wlane) *(f32x4*)(red + tt * RSTR + 4 * oct) = p;
    }
    // consumer: lane (hf, sr, cr) sums 4 octet-partials; banks 2-way (free)
    float acc = 0.f;
    #pragma unroll
    for (int k = 0; k < 4; ++k)
      acc += red[sr * RSTR + 16 * hf + 4 * k + cr];
    acc += __shfl_xor(acc, 32);
    if (hf == 0) ybuf[cr * 128 + ((c0 & 127) + sr)] = f2bf(acc);
    if (((c0 + HCHUNK) & 127) == 0) {
      int tw = (c0 + HCHUNK) - 128;   // window start within segment
      #pragma unroll
      for (int c = 0; c < NC; ++c) {
        unsigned v = *(const unsigned*)(ybuf + c * 128 + 2 * lane);
        *(unsigned*)(yo + (size_t)c * BATCH * SEQ + tw + 2 * lane) = v;
      }
    }
  }
}

// ---------------- gate: yg = (ysT^T + u*Dp) * silu(z) ----------------
__global__ __launch_bounds__(256) void k_gate(
    const u16* __restrict__ ysT, const u16* __restrict__ ub,
    const u16* __restrict__ xz, const float* __restrict__ Dp,
    u16* __restrict__ yg)
{
  __shared__ u16 tile[64][68];
  const int tid  = threadIdx.x;
  const int c    = tid & 63;
  const int rb   = tid >> 6;
  const int tok0 = blockIdx.x * 64;
  const int d0   = blockIdx.y * 64;
  const int bb   = tok0 >> 11;
  const int t0   = tok0 & (SEQ - 1);

  #pragma unroll
  for (int j = 0; j < 16; ++j) {
    int dl = rb + j * 4;
    tile[dl][c] = ysT[((size_t)(d0 + dl) * BATCH + bb) * SEQ + t0 + c];
  }
  __syncthreads();
  #pragma unroll
  for (int j = 0; j < 16; ++j) {
    int tl  = rb + j * 4;
    int tok = tok0 + tl;
    int dd  = d0 + c;
    float y = bf2f(tile[c][tl]);
    float uu = bf2f(ub[(size_t)tok * D_INNER + dd]);
    float z  = bf2f(xz[(size_t)tok * (2*D_INNER) + D_INNER + dd]);
    float v  = (y + uu * Dp[dd]) * (z / (1.0f + __expf(-z)));
    yg[(size_t)tok * D_INNER + dd] = f2bf(v);
  }
}

extern "C" void kernel_launch(void* const* d_in, const int* in_sizes, int n_in,
                              void* d_out, int out_size, void* d_ws, size_t ws_size,
                              hipStream_t stream) {
  (void)in_sizes; (void)n_in; (void)out_size;
  const float* x      = (const float*)d_in[0];
  const float* W_in   = (const float*)d_in[1];
  const float* W_out  = (const float*)d_in[2];
  const float* conv_w = (const float*)d_in[3];
  const float* conv_b = (const float*)d_in[4];
  const float* W_x    = (const float*)d_in[5];
  const float* W_dt   = (const float*)d_in[6];
  const float* b_dt   = (const float*)d_in[7];
  const float* A_log  = (const float*)d_in[8];
  const float* Dp     = (const float*)d_in[9];

  size_t off = 0;
  char* wsb = (char*)d_ws;
  auto alloc = [&](size_t bytes) -> void* {
    void* p = wsb + off;
    off += (bytes + 255) & ~(size_t)255;
    return p;
  };
  u16*    x_bf    = (u16*)alloc((size_t)TOKENS * D_MODEL * 2);
  u16*    Win_bf  = (u16*)alloc((size_t)2 * D_INNER * D_MODEL * 2);
  u16*    Wx_bf   = (u16*)alloc((size_t)NPROJ * D_INNER * 2);
  u16*    Wdt_bf  = (u16*)alloc((size_t)D_INNER * DT_RANK * 2);
  u16*    Wout_bf = (u16*)alloc((size_t)D_MODEL * D_INNER * 2);
  u16*    xz_bf   = (u16*)alloc((size_t)TOKENS * 2 * D_INNER * 2);
  u16*    u_bf    = (u16*)alloc((size_t)TOKENS * D_INNER * 2);
  float*  xdbl    = (float*)alloc((size_t)TOKENS * NPROJ * 4);
  u16*    dtlo_bf = (u16*)alloc((size_t)TOKENS * DT_RANK * 2);
  float*  BC_f    = (float*)alloc((size_t)TOKENS * 256 * 4);
  float*  dtqP    = (float*)alloc((size_t)TOKENS * D_INNER * 8);
  float*  Rbuf    = (float*)alloc((size_t)TOKENS * D_INNER * 4);
  u16*    ysT     = (u16*)alloc((size_t)D_INNER * TOKENS * 2);
  u16*    yg      = (u16*)alloc((size_t)TOKENS * D_INNER * 2);

  // pick largest nseg whose H+S scratch fits the remaining workspace
  int nseg = 1, lognseg = 0;
  for (int cand = 16, lg = 4; cand > 1; cand >>= 1, --lg) {
    size_t need = ((size_t)NCOL * cand * D_STATE * 4 + 255 + (size_t)NCOL * cand * 4 + 255);
    if (off + need <= ws_size) { nseg = cand; lognseg = lg; break; }
  }
  float* Hbuf = (float*)alloc((size_t)NCOL * nseg * D_STATE * 4);
  float* Sbuf = (float*)alloc((size_t)NCOL * nseg * 4);
  const int SL = SEQ / nseg;

  auto cvt = [&](const float* src, u16* dst, size_t n) {
    int n4 = (int)(n / 4);
    k_cvt_bf16<<<(n4 + 255) / 256, 256, 0, stream>>>(src, dst, n4);
  };
  cvt(x,     x_bf,    (size_t)TOKENS * D_MODEL);
  cvt(W_in,  Win_bf,  (size_t)2 * D_INNER * D_MODEL);
  cvt(W_x,   Wx_bf,   (size_t)NPROJ * D_INNER);
  cvt(W_dt,  Wdt_bf,  (size_t)D_INNER * DT_RANK);
  cvt(W_out, Wout_bf, (size_t)D_MODEL * D_INNER);

  dim3 blk(256);
  // 1) xz = x @ W_in^T -> bf16
  k_gemm_bt<1><<<dim3(TOKENS/128, (2*D_INNER)/128), blk, 0, stream>>>(
      x_bf, Win_bf, xz_bf, nullptr, nullptr, nullptr, TOKENS, 2*D_INNER, D_MODEL, 2*D_INNER);
  // 2) u = silu(conv(xc))
  k_conv_silu<<<(TOKENS * D_INNER) / 256, blk, 0, stream>>>(xz_bf, conv_w, conv_b, u_bf);
  // 3) x_dbl = u @ W_x^T (f32)
  k_gemm_bt<0><<<dim3(TOKENS/128, (NPROJ + 127)/128), blk, 0, stream>>>(
      u_bf, Wx_bf, xdbl, nullptr, nullptr, nullptr, TOKENS, NPROJ, D_INNER, NPROJ);
  // 4) split
  k_split<<<((TOKENS * NPROJ) + 255) / 256, blk, 0, stream>>>(xdbl, dtlo_bf, BC_f);
  // 5) dtq = {dt*l2e, dt*u}, R = e^{-dt}, both packed [d/4][tok][4]
  k_gemm_bt<3><<<dim3(TOKENS/128, D_INNER/128), blk, 0, stream>>>(
      dtlo_bf, Wdt_bf, dtqP, b_dt, u_bf, Rbuf, TOKENS, D_INNER, DT_RANK, 0);
  // 6) segmented scan (NC=4 cols/wave, 16 cols/block)
  if (nseg > 1) {
    k_scan_head<<<(NCOL / 16) * (nseg - 1), blk, 0, stream>>>(
        dtqP, Rbuf, BC_f, A_log, Hbuf, Sbuf, nseg, SL);
    k_stitch<<<NCOL / 4, blk, 0, stream>>>(A_log, Hbuf, Sbuf, nseg);
  }
  k_scan_main<<<(NCOL / 16) * nseg, blk, 0, stream>>>(
      dtqP, Rbuf, BC_f, A_log, Hbuf, ysT, nseg, lognseg, SL);
  // 7) gate
  k_gate<<<dim3(TOKENS/64, D_INNER/64), blk, 0, stream>>>(ysT, u_bf, xz_bf, Dp, yg);
  // 8) out = yg @ W_out^T -> f32
  k_gemm_bt<0><<<dim3(TOKENS/128, D_MODEL/128), blk, 0, stream>>>(
      yg, Wout_bf, d_out, nullptr, nullptr, nullptr, TOKENS, D_MODEL, D_INNER, D_MODEL);
}

// Round 10
// 660.346 us; speedup vs baseline: 1.3195x; 1.3195x over previous
//
#include <hip/hip_runtime.h>
#include <stdint.h>
#include <math.h>

#define D_MODEL 1024
#define D_STATE 128
#define D_INNER 2048
#define DT_RANK 64
#define BATCH   2
#define SEQ     2048
#define TOKENS  (BATCH*SEQ)        // 4096
#define NPROJ   (DT_RANK + 2*D_STATE) // 320
#define NCOL    (BATCH*D_INNER)    // 4096 scan columns

typedef unsigned short u16;
typedef __attribute__((ext_vector_type(4))) float f32x4;
typedef __attribute__((ext_vector_type(8))) short s16x8;
typedef __attribute__((ext_vector_type(4))) unsigned short u16x4;

#if __has_builtin(__builtin_amdgcn_exp2f)
#define EXP2(x) __builtin_amdgcn_exp2f(x)
#else
#define EXP2(x) __expf((x) * 0.6931471805599453f)
#endif
#define L2E 1.44269504088896f

static __device__ __forceinline__ u16 f2bf(float f) {
  unsigned u = __builtin_bit_cast(unsigned, f);
  return (u16)((u + 0x7FFFu + ((u >> 16) & 1u)) >> 16);
}
static __device__ __forceinline__ float bf2f(u16 h) {
  return __builtin_bit_cast(float, ((unsigned)h) << 16);
}

static __device__ __forceinline__ void gload_lds16(const void* g, void* l) {
  __builtin_amdgcn_global_load_lds(
      (const __attribute__((address_space(1))) void*)g,
      (__attribute__((address_space(3))) void*)l, 16, 0, 0);
}

// DPP add: x + dpp_shuffle(x)
template<int CTRL>
static __device__ __forceinline__ float dpp_add(float x) {
  int t = __builtin_amdgcn_update_dpp(0, __builtin_bit_cast(int, x), CTRL, 0xf, 0xf, true);
  return x + __builtin_bit_cast(float, t);
}
// sum over each 8-lane octet; valid in lane 8o+4 of each octet
static __device__ __forceinline__ float octet_sum(float x) {
  x = dpp_add<0xB1>(x);   // quad_perm(1,0,3,2): pair sum
  x = dpp_add<0x4E>(x);   // quad_perm(2,3,0,1): quad sum
  x = dpp_add<0x114>(x);  // row_shr:4: lane 8o+4 holds octet sum
  return x;
}

// ---------------- fp32 -> bf16 convert (vec4) ----------------
__global__ void k_cvt_bf16(const float* __restrict__ in, u16* __restrict__ out, int n4) {
  int i = blockIdx.x * blockDim.x + threadIdx.x;
  if (i >= n4) return;
  f32x4 v = ((const f32x4*)in)[i];
  u16x4 o;
  o.x = f2bf(v.x); o.y = f2bf(v.y); o.z = f2bf(v.z); o.w = f2bf(v.w);
  ((u16x4*)out)[i] = o;
}

// ---------------- bf16 GEMM: C = A @ B^T ----------------
// EPI: 0 = f32 store, 1 = bf16 store,
//      3 = dt path: v=softplus(acc+2*bias[col]);
//          store float2{v*l2e, v*u[row,col]} packed [(col/4)][row][col%4]
#define BM 128
#define BN 128
#define BK 64

template<int EPI>
__global__ __launch_bounds__(256) void k_gemm_bt(
    const u16* __restrict__ A, const u16* __restrict__ B,
    void* __restrict__ C, const float* __restrict__ bias,
    const u16* __restrict__ U,
    int M, int N, int K, int ldc)
{
  __shared__ __align__(16) u16 As[BM*BK];
  __shared__ __align__(16) u16 Bs[BN*BK];
  const int tid  = threadIdx.x;
  const int lane = tid & 63;
  const int wid  = tid >> 6;
  const int wr   = (wid >> 1) * 64;
  const int wc   = (wid & 1) * 64;
  const int bm   = blockIdx.x * BM;
  const int bn   = blockIdx.y * BN;
  const int lr   = lane & 15;
  const int lk   = (lane >> 4) * 8;

  f32x4 acc[4][4] = {};

  for (int k0 = 0; k0 < K; k0 += BK) {
    #pragma unroll
    for (int i = 0; i < 4; ++i) {
      int c   = tid + i * 256;
      int row = c >> 3;
      int col = (c & 7) * 8;
      const u16* ga = A + (size_t)(bm + row) * K + (k0 + col);
      gload_lds16(ga, As + (size_t)c * 8);
      int brow = bn + row; brow = brow < N ? brow : N - 1;
      const u16* gb = B + (size_t)brow * K + (k0 + col);
      gload_lds16(gb, Bs + (size_t)c * 8);
    }
    __syncthreads();

    #pragma unroll
    for (int kk = 0; kk < BK; kk += 32) {
      s16x8 af[4], bf[4];
      #pragma unroll
      for (int m = 0; m < 4; ++m)
        af[m] = *(const s16x8*)(As + (size_t)(wr + m*16 + lr) * BK + kk + lk);
      #pragma unroll
      for (int n = 0; n < 4; ++n)
        bf[n] = *(const s16x8*)(Bs + (size_t)(wc + n*16 + lr) * BK + kk + lk);
      #pragma unroll
      for (int m = 0; m < 4; ++m)
        #pragma unroll
        for (int n = 0; n < 4; ++n)
          acc[m][n] = __builtin_amdgcn_mfma_f32_16x16x32_bf16(af[m], bf[n], acc[m][n], 0, 0, 0);
    }
    __syncthreads();
  }

  const int orow0 = bm + wr + (lane >> 4) * 4;
  const int ocol0 = bn + wc + lr;
  #pragma unroll
  for (int m = 0; m < 4; ++m) {
    #pragma unroll
    for (int n = 0; n < 4; ++n) {
      int col = ocol0 + n * 16;
      if (col >= N) continue;
      #pragma unroll
      for (int r = 0; r < 4; ++r) {
        int row = orow0 + m * 16 + r;
        float v = acc[m][n][r];
        if (EPI == 3) {
          v = v + 2.0f * bias[col];
          v = (v > 20.0f) ? v : log1pf(__expf(v));
          float uu = bf2f(U[(size_t)row * D_INNER + col]);
          ((float2*)C)[(((size_t)(col >> 2) * TOKENS + row) << 2) + (col & 3)] =
              make_float2(v * L2E, v * uu);
        } else if (EPI == 1) {
          ((u16*)C)[(size_t)row * ldc + col] = f2bf(v);
        } else {
          ((float*)C)[(size_t)row * ldc + col] = v;
        }
      }
    }
  }
}

// ---------------- depthwise causal conv (K=4) + SiLU ----------------
__global__ __launch_bounds__(256) void k_conv_silu(
    const u16* __restrict__ xz, const float* __restrict__ cw,
    const float* __restrict__ cb, u16* __restrict__ u)
{
  int idx = blockIdx.x * 256 + threadIdx.x;
  int d   = idx & (D_INNER - 1);
  int tok = idx >> 11;
  int t   = tok & (SEQ - 1);
  int b   = tok >> 11;
  f32x4 w = *(const f32x4*)(cw + (size_t)d * 4);
  float acc = cb[d];
  #pragma unroll
  for (int j = 0; j < 4; ++j) {
    int tt = t - 3 + j;
    if (tt >= 0)
      acc += bf2f(xz[(size_t)(b * SEQ + tt) * (2*D_INNER) + d]) * w[j];
  }
  float s = acc / (1.0f + __expf(-acc));
  u[(size_t)tok * D_INNER + d] = f2bf(s);
}

// ---------------- split x_dbl -> dtlo bf16, interleaved BC f32 ----------------
// BC per token (256 f32): lane l gets {B2l, B2l+1, C2l, C2l+1} at 4*l
__global__ void k_split(const float* __restrict__ xdbl, u16* __restrict__ dtlo,
                        float* __restrict__ BC)
{
  int idx = blockIdx.x * 256 + threadIdx.x;
  if (idx >= TOKENS * NPROJ) return;
  int row = idx / NPROJ;
  int c   = idx - row * NPROJ;
  float v = xdbl[idx];
  if (c < DT_RANK) {
    dtlo[(size_t)row * DT_RANK + c] = f2bf(v);
  } else if (c < DT_RANK + D_STATE) {
    int n = c - DT_RANK;
    BC[(size_t)row * 256 + (n >> 1) * 4 + (n & 1)] = v;
  } else {
    int n = c - DT_RANK - D_STATE;
    BC[(size_t)row * 256 + (n >> 1) * 4 + 2 + (n & 1)] = v;
  }
}

// =================== segmented selective scan (NC=4 cols/wave) ===================
// dtqP: float2 {dt*l2e, dt*u} packed [d/4][tok][d%4]
// BC:   f32 interleaved [b][t][256]  ({B2l,B2l+1,C2l,C2l+1} per lane)
// H:    [col][nseg][128]; S: [col][nseg] (sum of dt*l2e)
// Lane holds states {2*lane, 2*lane+1} for each of 4 cols.
#define NC 4
#define HCHUNK 8
#define RSTR 36   // 8 octets * 4 cols + 4 pad: 2-way banks (free)

__global__ __launch_bounds__(256, 4) void k_scan_head(
    const float* __restrict__ dtqP, const float* __restrict__ BC,
    const float* __restrict__ A_log, float* __restrict__ H,
    float* __restrict__ S, int nseg, int SL)
{
  const int lane = threadIdx.x & 63;
  const int wid  = threadIdx.x >> 6;
  const int bid  = blockIdx.x;
  const int nsm1 = nseg - 1;
  const int grp  = bid / nsm1;
  const int s    = bid - grp * nsm1;
  const int col0 = grp * 16 + wid * NC;
  const int b    = col0 >> 11;
  const int d0   = col0 & (D_INNER - 1);

  float A0[NC], A1[NC];
  #pragma unroll
  for (int c = 0; c < NC; ++c) {
    float2 al = *(const float2*)(A_log + (size_t)(d0 + c) * D_STATE + 2 * lane);
    A0[c] = -__expf(al.x);
    A1[c] = -__expf(al.y);
  }
  float h0[NC] = {}, h1[NC] = {}, sum[NC] = {};

  const float* dq = dtqP + ((size_t)(d0 >> 2) * TOKENS + (size_t)b * SEQ + s * SL) * 8;
  asm("" : "+v"(dq));
  const float* BCb = BC + ((size_t)b * SEQ + s * SL) * 256 + 4 * lane;

  for (int c0 = 0; c0 < SL; c0 += 4) {
    #pragma unroll
    for (int tt = 0; tt < 4; ++tt) {
      const float* dqq = dq + (size_t)(c0 + tt) * 8;
      f32x4 q0 = *(const f32x4*)(dqq);
      f32x4 q1 = *(const f32x4*)(dqq + 4);
      float2 bb = *(const float2*)(BCb + (size_t)(c0 + tt) * 256);
      float dts[NC] = {q0.x, q0.z, q1.x, q1.z};
      float dus[NC] = {q0.y, q0.w, q1.y, q1.w};
      #pragma unroll
      for (int c = 0; c < NC; ++c) {
        sum[c] += dts[c];
        float dA0 = EXP2(dts[c] * A0[c]);
        float dA1 = EXP2(dts[c] * A1[c]);
        h0[c] = fmaf(dA0, h0[c], dus[c] * bb.x);
        h1[c] = fmaf(dA1, h1[c], dus[c] * bb.y);
      }
    }
  }
  #pragma unroll
  for (int c = 0; c < NC; ++c)
    *(float2*)(H + ((size_t)(col0 + c) * nseg + s) * D_STATE + 2 * lane) =
        make_float2(h0[c], h1[c]);
  if (lane == 0) {
    #pragma unroll
    for (int c = 0; c < NC; ++c)
      S[(size_t)(col0 + c) * nseg + s] = sum[c];
  }
}

__global__ __launch_bounds__(256) void k_stitch(
    const float* __restrict__ A_log, float* __restrict__ H,
    const float* __restrict__ S, int nseg)
{
  const int lane = threadIdx.x & 63;
  const int wid  = threadIdx.x >> 6;
  const int col  = blockIdx.x * 4 + wid;
  const int d = col & (D_INNER - 1);

  float2 al = *(const float2*)(A_log + (size_t)d * D_STATE + 2 * lane);
  const float A0 = -__expf(al.x);
  const float A1 = -__expf(al.y);
  float hin0 = 0.f, hin1 = 0.f;

  for (int s = 0; s < nseg - 1; ++s) {
    float2* hp = (float2*)(H + ((size_t)col * nseg + s) * D_STATE + 2 * lane);
    float2 he = *hp;
    float sm = S[(size_t)col * nseg + s];
    float d0 = EXP2(A0 * sm);
    float d1 = EXP2(A1 * sm);
    hin0 = fmaf(d0, hin0, he.x);
    hin1 = fmaf(d1, hin1, he.y);
    *hp = make_float2(hin0, hin1);
  }
}

__global__ __launch_bounds__(256, 8) void k_scan_main(
    const float* __restrict__ dtqP, const float* __restrict__ BC,
    const float* __restrict__ A_log, const float* __restrict__ H,
    u16* __restrict__ ysT, int nseg, int lognseg, int SL)
{
  __shared__ float reds[4][HCHUNK * RSTR];   // 4 x 1152B
  __shared__ u16 ybufs[4][NC * 128];         // 4 x 1KB
  const int lane = threadIdx.x & 63;
  const int wid  = threadIdx.x >> 6;
  const unsigned bid = blockIdx.x;
  const int seg  = bid & (nseg - 1);
  const int grp  = bid >> lognseg;
  const int col0 = grp * 16 + wid * NC;
  const int b    = col0 >> 11;
  const int d0   = col0 & (D_INNER - 1);

  float A0[NC], A1[NC];
  #pragma unroll
  for (int c = 0; c < NC; ++c) {
    float2 al = *(const float2*)(A_log + (size_t)(d0 + c) * D_STATE + 2 * lane);
    A0[c] = -__expf(al.x);
    A1[c] = -__expf(al.y);
  }
  float h0[NC] = {}, h1[NC] = {};
  if (seg > 0) {
    #pragma unroll
    for (int c = 0; c < NC; ++c) {
      float2 hv = *(const float2*)(H + ((size_t)(col0 + c) * nseg + seg - 1) * D_STATE + 2 * lane);
      h0[c] = hv.x; h1[c] = hv.y;
    }
  }

  const int t0g = seg * SL;
  const float* dq = dtqP + ((size_t)(d0 >> 2) * TOKENS + (size_t)b * SEQ + t0g) * 8;
  asm("" : "+v"(dq));
  const float* BCb = BC + ((size_t)b * SEQ + t0g) * 256 + 4 * lane;
  float* red = reds[wid];
  u16* ybuf = ybufs[wid];
  const int o  = lane & 31;
  const int sr = o >> 2;       // step within chunk this lane reduces
  const int cr = o & 3;        // col this lane reduces
  const int hf = lane >> 5;    // which 4 octets this lane sums
  const bool wlane = (lane & 7) == 4;   // octet writer
  const int oct = lane >> 3;
  u16* yo = ysT + ((size_t)d0 * BATCH + b) * SEQ + t0g;

  for (int c0 = 0; c0 < SL; c0 += HCHUNK) {
    #pragma unroll
    for (int tt = 0; tt < HCHUNK; ++tt) {
      const float* dqq = dq + (size_t)(c0 + tt) * 8;
      f32x4 q0 = *(const f32x4*)(dqq);
      f32x4 q1 = *(const f32x4*)(dqq + 4);
      f32x4 bc = *(const f32x4*)(BCb + (size_t)(c0 + tt) * 256);
      float dts[NC] = {q0.x, q0.z, q1.x, q1.z};
      float dus[NC] = {q0.y, q0.w, q1.y, q1.w};
      f32x4 p;
      #pragma unroll
      for (int c = 0; c < NC; ++c) {
        float dA0 = EXP2(dts[c] * A0[c]);
        float dA1 = EXP2(dts[c] * A1[c]);
        h0[c] = fmaf(dA0, h0[c], dus[c] * bc.x);
        h1[c] = fmaf(dA1, h1[c], dus[c] * bc.y);
        p[c] = fmaf(h1[c], bc.w, h0[c] * bc.z);
      }
      // in-register octet reduction (VALU pipe) -> 1/8 LDS traffic
      #pragma unroll
      for (int c = 0; c < NC; ++c) p[c] = octet_sum(p[c]);
      if (wlane) *(f32x4*)(red + tt * RSTR + 4 * oct) = p;
    }
    // consumer: lane (hf, sr, cr) sums 4 octet-partials (2-way banks, free)
    float acc = 0.f;
    #pragma unroll
    for (int k = 0; k < 4; ++k)
      acc += red[sr * RSTR + 16 * hf + 4 * k + cr];
    acc += __shfl_xor(acc, 32);
    if (hf == 0) ybuf[cr * 128 + ((c0 & 127) + sr)] = f2bf(acc);
    if (((c0 + HCHUNK) & 127) == 0) {
      int tw = (c0 + HCHUNK) - 128;   // window start within segment
      #pragma unroll
      for (int c = 0; c < NC; ++c) {
        unsigned v = *(const unsigned*)(ybuf + c * 128 + 2 * lane);
        *(unsigned*)(yo + (size_t)c * BATCH * SEQ + tw + 2 * lane) = v;
      }
    }
  }
}

// ---------------- gate: yg = (ysT^T + u*Dp) * silu(z) ----------------
__global__ __launch_bounds__(256) void k_gate(
    const u16* __restrict__ ysT, const u16* __restrict__ ub,
    const u16* __restrict__ xz, const float* __restrict__ Dp,
    u16* __restrict__ yg)
{
  __shared__ u16 tile[64][68];
  const int tid  = threadIdx.x;
  const int c    = tid & 63;
  const int rb   = tid >> 6;
  const int tok0 = blockIdx.x * 64;
  const int d0   = blockIdx.y * 64;
  const int bb   = tok0 >> 11;
  const int t0   = tok0 & (SEQ - 1);

  #pragma unroll
  for (int j = 0; j < 16; ++j) {
    int dl = rb + j * 4;
    tile[dl][c] = ysT[((size_t)(d0 + dl) * BATCH + bb) * SEQ + t0 + c];
  }
  __syncthreads();
  #pragma unroll
  for (int j = 0; j < 16; ++j) {
    int tl  = rb + j * 4;
    int tok = tok0 + tl;
    int dd  = d0 + c;
    float y = bf2f(tile[c][tl]);
    float uu = bf2f(ub[(size_t)tok * D_INNER + dd]);
    float z  = bf2f(xz[(size_t)tok * (2*D_INNER) + D_INNER + dd]);
    float v  = (y + uu * Dp[dd]) * (z / (1.0f + __expf(-z)));
    yg[(size_t)tok * D_INNER + dd] = f2bf(v);
  }
}

extern "C" void kernel_launch(void* const* d_in, const int* in_sizes, int n_in,
                              void* d_out, int out_size, void* d_ws, size_t ws_size,
                              hipStream_t stream) {
  (void)in_sizes; (void)n_in; (void)out_size;
  const float* x      = (const float*)d_in[0];
  const float* W_in   = (const float*)d_in[1];
  const float* W_out  = (const float*)d_in[2];
  const float* conv_w = (const float*)d_in[3];
  const float* conv_b = (const float*)d_in[4];
  const float* W_x    = (const float*)d_in[5];
  const float* W_dt   = (const float*)d_in[6];
  const float* b_dt   = (const float*)d_in[7];
  const float* A_log  = (const float*)d_in[8];
  const float* Dp     = (const float*)d_in[9];

  size_t off = 0;
  char* wsb = (char*)d_ws;
  auto alloc = [&](size_t bytes) -> void* {
    void* p = wsb + off;
    off += (bytes + 255) & ~(size_t)255;
    return p;
  };
  u16*    x_bf    = (u16*)alloc((size_t)TOKENS * D_MODEL * 2);
  u16*    Win_bf  = (u16*)alloc((size_t)2 * D_INNER * D_MODEL * 2);
  u16*    Wx_bf   = (u16*)alloc((size_t)NPROJ * D_INNER * 2);
  u16*    Wdt_bf  = (u16*)alloc((size_t)D_INNER * DT_RANK * 2);
  u16*    Wout_bf = (u16*)alloc((size_t)D_MODEL * D_INNER * 2);
  u16*    xz_bf   = (u16*)alloc((size_t)TOKENS * 2 * D_INNER * 2);
  u16*    u_bf    = (u16*)alloc((size_t)TOKENS * D_INNER * 2);
  float*  xdbl    = (float*)alloc((size_t)TOKENS * NPROJ * 4);
  u16*    dtlo_bf = (u16*)alloc((size_t)TOKENS * DT_RANK * 2);
  float*  BC_f    = (float*)alloc((size_t)TOKENS * 256 * 4);
  float*  dtqP    = (float*)alloc((size_t)TOKENS * D_INNER * 8);
  u16*    ysT     = (u16*)alloc((size_t)D_INNER * TOKENS * 2);
  u16*    yg      = (u16*)alloc((size_t)TOKENS * D_INNER * 2);

  // pick largest nseg whose H+S scratch fits the remaining workspace
  int nseg = 1, lognseg = 0;
  for (int cand = 16, lg = 4; cand > 1; cand >>= 1, --lg) {
    size_t need = ((size_t)NCOL * cand * D_STATE * 4 + 255 + (size_t)NCOL * cand * 4 + 255);
    if (off + need <= ws_size) { nseg = cand; lognseg = lg; break; }
  }
  float* Hbuf = (float*)alloc((size_t)NCOL * nseg * D_STATE * 4);
  float* Sbuf = (float*)alloc((size_t)NCOL * nseg * 4);
  const int SL = SEQ / nseg;

  auto cvt = [&](const float* src, u16* dst, size_t n) {
    int n4 = (int)(n / 4);
    k_cvt_bf16<<<(n4 + 255) / 256, 256, 0, stream>>>(src, dst, n4);
  };
  cvt(x,     x_bf,    (size_t)TOKENS * D_MODEL);
  cvt(W_in,  Win_bf,  (size_t)2 * D_INNER * D_MODEL);
  cvt(W_x,   Wx_bf,   (size_t)NPROJ * D_INNER);
  cvt(W_dt,  Wdt_bf,  (size_t)D_INNER * DT_RANK);
  cvt(W_out, Wout_bf, (size_t)D_MODEL * D_INNER);

  dim3 blk(256);
  // 1) xz = x @ W_in^T -> bf16
  k_gemm_bt<1><<<dim3(TOKENS/128, (2*D_INNER)/128), blk, 0, stream>>>(
      x_bf, Win_bf, xz_bf, nullptr, nullptr, TOKENS, 2*D_INNER, D_MODEL, 2*D_INNER);
  // 2) u = silu(conv(xc))
  k_conv_silu<<<(TOKENS * D_INNER) / 256, blk, 0, stream>>>(xz_bf, conv_w, conv_b, u_bf);
  // 3) x_dbl = u @ W_x^T (f32)
  k_gemm_bt<0><<<dim3(TOKENS/128, (NPROJ + 127)/128), blk, 0, stream>>>(
      u_bf, Wx_bf, xdbl, nullptr, nullptr, TOKENS, NPROJ, D_INNER, NPROJ);
  // 4) split
  k_split<<<((TOKENS * NPROJ) + 255) / 256, blk, 0, stream>>>(xdbl, dtlo_bf, BC_f);
  // 5) dtq = {dt*l2e, dt*u} packed [d/4][tok][4]
  k_gemm_bt<3><<<dim3(TOKENS/128, D_INNER/128), blk, 0, stream>>>(
      dtlo_bf, Wdt_bf, dtqP, b_dt, u_bf, TOKENS, D_INNER, DT_RANK, 0);
  // 6) segmented scan (NC=4 cols/wave, 16 cols/block)
  if (nseg > 1) {
    k_scan_head<<<(NCOL / 16) * (nseg - 1), blk, 0, stream>>>(
        dtqP, BC_f, A_log, Hbuf, Sbuf, nseg, SL);
    k_stitch<<<NCOL / 4, blk, 0, stream>>>(A_log, Hbuf, Sbuf, nseg);
  }
  k_scan_main<<<(NCOL / 16) * nseg, blk, 0, stream>>>(
      dtqP, BC_f, A_log, Hbuf, ysT, nseg, lognseg, SL);
  // 7) gate
  k_gate<<<dim3(TOKENS/64, D_INNER/64), blk, 0, stream>>>(ysT, u_bf, xz_bf, Dp, yg);
  // 8) out = yg @ W_out^T -> f32
  k_gemm_bt<0><<<dim3(TOKENS/128, D_MODEL/128), blk, 0, stream>>>(
      yg, Wout_bf, d_out, nullptr, nullptr, TOKENS, D_MODEL, D_INNER, D_MODEL);
}